// Round 1
// baseline (238.744 us; speedup 1.0000x reference)
//
#include <hip/hip_runtime.h>

#define B_DIM 4
#define T_DIM 4096
#define C_DIM 2048
#define KK 4
#define TT 16          // t-steps per thread; halo overhead = 3/16 (L2/L3-absorbed)
#define C4 (C_DIM / 4) // 512 float4 lanes across channels

typedef float v4f __attribute__((ext_vector_type(4)));

// Single-phase structure: ALL loads issued before ANY store.
// Rationale: vmcnt counts stores and retires in issue order, so the previous
// chunked [loads][stores][loads]... layout forced each chunk's compute to wait
// for the prior chunk's NT stores to fully complete (store-drain stall).
// With loads-first, every buf[j] wait is vmcnt(~15) and store completion is
// never on the critical path. MLP/wave: 8 -> 19.
__global__ __launch_bounds__(256) void canonconv_kernel(
    const float* __restrict__ x,
    const float* __restrict__ w,
    const float* __restrict__ bias,
    float* __restrict__ out)
{
    const int idx   = blockIdx.x * blockDim.x + threadIdx.x;
    const int c4    = idx % C4;            // which float4 channel group
    const int tmp   = idx / C4;            // block-uniform (256-thread block never crosses a 512 boundary)
    const int ttile = tmp % (T_DIM / TT);
    const int b     = tmp / (T_DIM / TT);
    const int t0    = ttile * TT;
    const int c     = c4 * 4;

    // --- weight/bias loads FIRST in program order: they are needed at j=0, and
    // in-order vmcnt retirement means anything issued after the x-loads would
    // force a full drain before compute starts.
    const v4f* wv = (const v4f*)(w + (size_t)c * KK);
    const v4f a0 = wv[0];  // (w[c,0], w[c,1], w[c,2], w[c,3])
    const v4f a1 = wv[1];
    const v4f a2 = wv[2];
    const v4f a3 = wv[3];
    const v4f bv = *(const v4f*)(bias + c);

    const float* xb = x   + ((size_t)b * T_DIM) * C_DIM + c;
    float*       ob = out + ((size_t)b * T_DIM) * C_DIM + c;

    // --- halo loads (zeros before t=0; branch is block-uniform)
    v4f xm3, xm2, xm1;
    const bool interior = (t0 != 0);
    if (interior) {
        xm3 = *(const v4f*)(xb + (size_t)(t0 - 3) * C_DIM);
        xm2 = *(const v4f*)(xb + (size_t)(t0 - 2) * C_DIM);
        xm1 = *(const v4f*)(xb + (size_t)(t0 - 1) * C_DIM);
    }

    // --- body: batch-issue all 16 t-step loads (19 x-loads in flight total)
    v4f buf[TT];
    #pragma unroll
    for (int j = 0; j < TT; ++j) {
        buf[j] = *(const v4f*)(xb + (size_t)(t0 + j) * C_DIM);
    }

    if (!interior) {
        xm3 = (v4f)0.0f;
        xm2 = (v4f)0.0f;
        xm1 = (v4f)0.0f;
    }

    // --- transpose weights to per-tap vectors (pure VALU, overlaps load latency)
    v4f tap0, tap1, tap2, tap3;
    tap0.x = a0.x; tap0.y = a1.x; tap0.z = a2.x; tap0.w = a3.x; // coeff on x[t-3]
    tap1.x = a0.y; tap1.y = a1.y; tap1.z = a2.y; tap1.w = a3.y; // x[t-2]
    tap2.x = a0.z; tap2.y = a1.z; tap2.z = a2.z; tap2.w = a3.z; // x[t-1]
    // tap on x[t] fused with residual: (1 + w[c,3])
    tap3.x = 1.0f + a0.w; tap3.y = 1.0f + a1.w; tap3.z = 1.0f + a2.w; tap3.w = 1.0f + a3.w;

    // --- compute + store; loads retire in order so each j waits for exactly
    // one more load, never for a store.
    #pragma unroll
    for (int j = 0; j < TT; ++j) {
        const v4f xc = buf[j];
        v4f r;
        r.x = fmaf(xc.x, tap3.x, fmaf(xm1.x, tap2.x, fmaf(xm2.x, tap1.x, fmaf(xm3.x, tap0.x, bv.x))));
        r.y = fmaf(xc.y, tap3.y, fmaf(xm1.y, tap2.y, fmaf(xm2.y, tap1.y, fmaf(xm3.y, tap0.y, bv.y))));
        r.z = fmaf(xc.z, tap3.z, fmaf(xm1.z, tap2.z, fmaf(xm2.z, tap1.z, fmaf(xm3.z, tap0.z, bv.z))));
        r.w = fmaf(xc.w, tap3.w, fmaf(xm1.w, tap2.w, fmaf(xm2.w, tap1.w, fmaf(xm3.w, tap0.w, bv.w))));
        __builtin_nontemporal_store(r, (v4f*)(ob + (size_t)(t0 + j) * C_DIM));
        xm3 = xm2;
        xm2 = xm1;
        xm1 = xc;
    }
}

extern "C" void kernel_launch(void* const* d_in, const int* in_sizes, int n_in,
                              void* d_out, int out_size, void* d_ws, size_t ws_size,
                              hipStream_t stream) {
    const float* x    = (const float*)d_in[0];
    const float* w    = (const float*)d_in[1];
    const float* bias = (const float*)d_in[2];
    float* out = (float*)d_out;

    const int total_threads = B_DIM * (T_DIM / TT) * C4; // 4*256*512 = 524288
    const int block = 256;
    const int grid  = total_threads / block;             // 2048
    canonconv_kernel<<<grid, block, 0, stream>>>(x, w, bias, out);
}

// Round 2
// 237.658 us; speedup vs baseline: 1.0046x; 1.0046x over previous
//
#include <hip/hip_runtime.h>

#define B_DIM 4
#define T_DIM 4096
#define C_DIM 2048
#define KK 4
#define TT 16          // t-steps per thread; halo overhead = 3/16 (L2/L3-absorbed)
#define C4 (C_DIM / 4) // 512 float4 lanes across channels

typedef float v4f __attribute__((ext_vector_type(4)));

// Single-phase structure: ALL loads issued before ANY store, ENFORCED with
// sched_barrier(0). Round-1 lesson: without the fence, the LLVM scheduler
// sinks the batched loads back into the compute loop to minimize register
// pressure (VGPR stayed at 28), re-creating the interleaved schedule whose
// buf[j] waits are gated on NT-store completion (vmcnt counts stores,
// retirement is in issue order). The fence pins: 24 loads in flight ->
// every compute wait satisfied by load retirement alone. ~105 VGPR,
// 4 waves/SIMD, ~4.9 KB reads in flight per CU (vs ~3 KB before).
__global__ __launch_bounds__(256) void canonconv_kernel(
    const float* __restrict__ x,
    const float* __restrict__ w,
    const float* __restrict__ bias,
    float* __restrict__ out)
{
    const int idx   = blockIdx.x * blockDim.x + threadIdx.x;
    const int c4    = idx % C4;            // which float4 channel group
    const int tmp   = idx / C4;            // block-uniform (256-thread block never crosses a 512 boundary)
    const int ttile = tmp % (T_DIM / TT);
    const int b     = tmp / (T_DIM / TT);
    const int t0    = ttile * TT;
    const int c     = c4 * 4;

    // --- weight/bias loads first (needed earliest; loads retire in order)
    const v4f* wv = (const v4f*)(w + (size_t)c * KK);
    const v4f a0 = wv[0];  // (w[c,0], w[c,1], w[c,2], w[c,3])
    const v4f a1 = wv[1];
    const v4f a2 = wv[2];
    const v4f a3 = wv[3];
    const v4f bv = *(const v4f*)(bias + c);

    const float* xb = x   + ((size_t)b * T_DIM) * C_DIM + c;
    float*       ob = out + ((size_t)b * T_DIM) * C_DIM + c;

    // --- halo loads (zeros before t=0; branch is block-uniform)
    v4f xm3, xm2, xm1;
    const bool interior = (t0 != 0);
    if (interior) {
        xm3 = *(const v4f*)(xb + (size_t)(t0 - 3) * C_DIM);
        xm2 = *(const v4f*)(xb + (size_t)(t0 - 2) * C_DIM);
        xm1 = *(const v4f*)(xb + (size_t)(t0 - 1) * C_DIM);
    }

    // --- body: batch-issue all 16 t-step loads (19 x-loads in flight total)
    v4f buf[TT];
    #pragma unroll
    for (int j = 0; j < TT; ++j) {
        buf[j] = *(const v4f*)(xb + (size_t)(t0 + j) * C_DIM);
    }

    // FENCE: nothing may cross. Loads above cannot be sunk into the
    // compute/store region below; stores below cannot be hoisted above.
    __builtin_amdgcn_sched_barrier(0);

    if (!interior) {
        xm3 = (v4f)0.0f;
        xm2 = (v4f)0.0f;
        xm1 = (v4f)0.0f;
    }

    // --- transpose weights to per-tap vectors (pure VALU, overlaps load latency)
    v4f tap0, tap1, tap2, tap3;
    tap0.x = a0.x; tap0.y = a1.x; tap0.z = a2.x; tap0.w = a3.x; // coeff on x[t-3]
    tap1.x = a0.y; tap1.y = a1.y; tap1.z = a2.y; tap1.w = a3.y; // x[t-2]
    tap2.x = a0.z; tap2.y = a1.z; tap2.z = a2.z; tap2.w = a3.z; // x[t-1]
    // tap on x[t] fused with residual: (1 + w[c,3])
    tap3.x = 1.0f + a0.w; tap3.y = 1.0f + a1.w; tap3.z = 1.0f + a2.w; tap3.w = 1.0f + a3.w;

    // --- compute + store; loads retire in order so the wait before using
    // buf[j] is a loose vmcnt satisfied by load completion; stores issued
    // here only loosen subsequent waits, never tighten them.
    #pragma unroll
    for (int j = 0; j < TT; ++j) {
        const v4f xc = buf[j];
        v4f r;
        r.x = fmaf(xc.x, tap3.x, fmaf(xm1.x, tap2.x, fmaf(xm2.x, tap1.x, fmaf(xm3.x, tap0.x, bv.x))));
        r.y = fmaf(xc.y, tap3.y, fmaf(xm1.y, tap2.y, fmaf(xm2.y, tap1.y, fmaf(xm3.y, tap0.y, bv.y))));
        r.z = fmaf(xc.z, tap3.z, fmaf(xm1.z, tap2.z, fmaf(xm2.z, tap1.z, fmaf(xm3.z, tap0.z, bv.z))));
        r.w = fmaf(xc.w, tap3.w, fmaf(xm1.w, tap2.w, fmaf(xm2.w, tap1.w, fmaf(xm3.w, tap0.w, bv.w))));
        __builtin_nontemporal_store(r, (v4f*)(ob + (size_t)(t0 + j) * C_DIM));
        xm3 = xm2;
        xm2 = xm1;
        xm1 = xc;
    }
}

extern "C" void kernel_launch(void* const* d_in, const int* in_sizes, int n_in,
                              void* d_out, int out_size, void* d_ws, size_t ws_size,
                              hipStream_t stream) {
    const float* x    = (const float*)d_in[0];
    const float* w    = (const float*)d_in[1];
    const float* bias = (const float*)d_in[2];
    float* out = (float*)d_out;

    const int total_threads = B_DIM * (T_DIM / TT) * C4; // 4*256*512 = 524288
    const int block = 256;
    const int grid  = total_threads / block;             // 2048
    canonconv_kernel<<<grid, block, 0, stream>>>(x, w, bias, out);
}

// Round 3
// 236.771 us; speedup vs baseline: 1.0083x; 1.0037x over previous
//
#include <hip/hip_runtime.h>

#define B_DIM 4
#define T_DIM 4096
#define C_DIM 2048
#define KK 4
#define TT 16          // t-steps per thread; halo overhead = 3/16 (L2/L3-absorbed)
#define C4 (C_DIM / 4) // 512 float4 lanes across channels

typedef float v4f __attribute__((ext_vector_type(4)));

// R3: single-variable experiment vs R1 — PLAIN stores instead of
// __builtin_nontemporal_store. Evidence: three schedule variants (interleaved,
// compiler-sunk, fenced 19-deep batch) all pinned at 2.55 TB/s -> schedule-
// insensitive, memory-system-limited. Same-trace fillBuffer (plain stores)
// does 6.64 TB/s; m13 float4 copy (plain, mixed R+W) does 6.29 TB/s. The nt
// write path is the prime suspect for the 2.5x gap. Fence removed (proven
// null; restores the known 28-VGPR high-occupancy codegen).
__global__ __launch_bounds__(256) void canonconv_kernel(
    const float* __restrict__ x,
    const float* __restrict__ w,
    const float* __restrict__ bias,
    float* __restrict__ out)
{
    const int idx   = blockIdx.x * blockDim.x + threadIdx.x;
    const int c4    = idx % C4;            // which float4 channel group
    const int tmp   = idx / C4;            // block-uniform (256-thread block never crosses a 512 boundary)
    const int ttile = tmp % (T_DIM / TT);
    const int b     = tmp / (T_DIM / TT);
    const int t0    = ttile * TT;
    const int c     = c4 * 4;

    // --- weight/bias loads
    const v4f* wv = (const v4f*)(w + (size_t)c * KK);
    const v4f a0 = wv[0];  // (w[c,0], w[c,1], w[c,2], w[c,3])
    const v4f a1 = wv[1];
    const v4f a2 = wv[2];
    const v4f a3 = wv[3];
    const v4f bv = *(const v4f*)(bias + c);

    const float* xb = x   + ((size_t)b * T_DIM) * C_DIM + c;
    float*       ob = out + ((size_t)b * T_DIM) * C_DIM + c;

    // --- halo loads (zeros before t=0; branch is block-uniform)
    v4f xm3, xm2, xm1;
    const bool interior = (t0 != 0);
    if (interior) {
        xm3 = *(const v4f*)(xb + (size_t)(t0 - 3) * C_DIM);
        xm2 = *(const v4f*)(xb + (size_t)(t0 - 2) * C_DIM);
        xm1 = *(const v4f*)(xb + (size_t)(t0 - 1) * C_DIM);
    }

    // --- body loads (compiler will interleave with compute; proven
    // perf-equivalent to the fenced batch, and keeps VGPR at ~28 ->
    // 8 waves/SIMD available)
    v4f buf[TT];
    #pragma unroll
    for (int j = 0; j < TT; ++j) {
        buf[j] = *(const v4f*)(xb + (size_t)(t0 + j) * C_DIM);
    }

    if (!interior) {
        xm3 = (v4f)0.0f;
        xm2 = (v4f)0.0f;
        xm1 = (v4f)0.0f;
    }

    // --- transpose weights to per-tap vectors
    v4f tap0, tap1, tap2, tap3;
    tap0.x = a0.x; tap0.y = a1.x; tap0.z = a2.x; tap0.w = a3.x; // coeff on x[t-3]
    tap1.x = a0.y; tap1.y = a1.y; tap1.z = a2.y; tap1.w = a3.y; // x[t-2]
    tap2.x = a0.z; tap2.y = a1.z; tap2.z = a2.z; tap2.w = a3.z; // x[t-1]
    // tap on x[t] fused with residual: (1 + w[c,3])
    tap3.x = 1.0f + a0.w; tap3.y = 1.0f + a1.w; tap3.z = 1.0f + a2.w; tap3.w = 1.0f + a3.w;

    // --- compute + PLAIN stores (the experiment variable)
    #pragma unroll
    for (int j = 0; j < TT; ++j) {
        const v4f xc = buf[j];
        v4f r;
        r.x = fmaf(xc.x, tap3.x, fmaf(xm1.x, tap2.x, fmaf(xm2.x, tap1.x, fmaf(xm3.x, tap0.x, bv.x))));
        r.y = fmaf(xc.y, tap3.y, fmaf(xm1.y, tap2.y, fmaf(xm2.y, tap1.y, fmaf(xm3.y, tap0.y, bv.y))));
        r.z = fmaf(xc.z, tap3.z, fmaf(xm1.z, tap2.z, fmaf(xm2.z, tap1.z, fmaf(xm3.z, tap0.z, bv.z))));
        r.w = fmaf(xc.w, tap3.w, fmaf(xm1.w, tap2.w, fmaf(xm2.w, tap1.w, fmaf(xm3.w, tap0.w, bv.w))));
        *(v4f*)(ob + (size_t)(t0 + j) * C_DIM) = r;
        xm3 = xm2;
        xm2 = xm1;
        xm1 = xc;
    }
}

extern "C" void kernel_launch(void* const* d_in, const int* in_sizes, int n_in,
                              void* d_out, int out_size, void* d_ws, size_t ws_size,
                              hipStream_t stream) {
    const float* x    = (const float*)d_in[0];
    const float* w    = (const float*)d_in[1];
    const float* bias = (const float*)d_in[2];
    float* out = (float*)d_out;

    const int total_threads = B_DIM * (T_DIM / TT) * C4; // 4*256*512 = 524288
    const int block = 256;
    const int grid  = total_threads / block;             // 2048
    canonconv_kernel<<<grid, block, 0, stream>>>(x, w, bias, out);
}